// Round 16
// baseline (17.000 us; speedup 1.0000x reference)
//
#include <hip/hip_runtime.h>
#include <stdint.h>

typedef __attribute__((ext_vector_type(8))) short short8;
typedef __attribute__((ext_vector_type(4))) float f32x4;

namespace {
constexpr int   kN     = 50;
constexpr int   kD     = 128;
constexpr float kNeg   = -9.0e15f;
constexpr float kSlope = 0.2f;
constexpr int   HS16   = 136;   // Hhi/Hlo row stride (shorts), 16B-aligned rows
constexpr int   ADS    = 52;    // adj byte stride
constexpr int   HTW    = 66;    // Hti row stride (u32 words)
constexpr int   PW     = 72;    // Pw2 row stride (shorts)
constexpr int   XS     = 20;    // Xch inner stride (f32)
}

union Pack8 { uint32_t u[4]; short8 s; };

// interleaved hi|lo bf16 pack: low short = hi-bf16(v), high short = lo-bf16(v - hi)
__device__ __forceinline__ uint32_t pack_hl(float v) {
    const uint32_t b  = __float_as_uint(v);
    const uint32_t hi = b & 0xffff0000u;
    const float    r  = v - __uint_as_float(hi);
    return (b >> 16) | (__float_as_uint(r) & 0xffff0000u);
}

__global__ __launch_bounds__(512)
void gat_v16_kernel(const float* __restrict__ hidden,
                    const int*   __restrict__ adj,
                    const float* __restrict__ a0,
                    const float* __restrict__ a1,
                    const float* __restrict__ a2,
                    const float* __restrict__ a3,
                    float* __restrict__ out)
{
    __shared__ unsigned short Hhi[64 * HS16];   // 17.0 KB bf16 hi(H) rows, j>=50 zero
    __shared__ unsigned short Hlo[64 * HS16];   // 17.0 KB bf16 lo(H)
    __shared__ uint32_t       Hti[128 * HTW];   // 33.0 KB transposed H [d][j], hi|lo interleaved
    __shared__ unsigned char  Ad [kN * ADS];    //  2.5 KB adj bytes
    __shared__ float          Xch[8][64][XS];   // 40.0 KB K-half exchange
    __shared__ unsigned short Pw2[8][16 * PW];  // 18.0 KB per-wave P [i][j] bf16
    // total 127.5 KB -> 1 block/CU, 8 waves

    const int b    = blockIdx.x;
    const int tid  = threadIdx.x;
    const int lane = tid & 63;
    const int wid  = __builtin_amdgcn_readfirstlane(tid >> 6);  // 0..7
    const int g    = lane >> 4;
    const int f    = lane & 15;

    const float* __restrict__ hb   = hidden + (size_t)b * (kN * kD);
    const int*   __restrict__ adjb = adj    + (size_t)b * (kN * kN);
    float*       __restrict__ outb = out    + (size_t)b * (kN * kD);

    // wave roles (known pre-barrier)
    const int it   = wid & 3;
    const int kh   = wid >> 2;
    const int i0   = 16 * it;
    const int irow = (i0 + f < kN) ? (i0 + f) : (kN - 1);

    // ---------------- phase 1 pre-barrier register fetches (T14 issue-early) ----------------
    // (a) a_k slices for BOTH ksl2 iterations -> registers (compiler can't hoist past barrier)
    const float* __restrict__ aks[4] = {a0, a1, a2, a3};
    float4 qa[2][4][2];                         // [ksl2][k][half]
    #pragma unroll
    for (int ksl2 = 0; ksl2 < 2; ++ksl2) {
        const int dofs = 64 * kh + 32 * ksl2 + 8 * g;
        #pragma unroll
        for (int k = 0; k < 4; ++k) {
            qa[ksl2][k][0] = *reinterpret_cast<const float4*>(aks[k] + dofs);
            qa[ksl2][k][1] = *reinterpret_cast<const float4*>(aks[k] + dofs + 4);
        }
    }
    // (b) A-side h_i direct from global, exact f32 (replaces post-barrier LDS + reconstruct)
    float4 hA[2][2];                            // [ksl2][half]
    #pragma unroll
    for (int ksl2 = 0; ksl2 < 2; ++ksl2) {
        const int dofs = 64 * kh + 32 * ksl2 + 8 * g;
        hA[ksl2][0] = *reinterpret_cast<const float4*>(hb + irow * kD + dofs);
        hA[ksl2][1] = *reinterpret_cast<const float4*>(hb + irow * kD + dofs + 4);
    }
    // (c) Hti transpose source -> registers
    const float2* hb2 = reinterpret_cast<const float2*>(hb);
    float2 tv0[4], tv1[4];
    #pragma unroll
    for (int it4 = 0; it4 < 4; ++it4) {
        const int jp = wid + 8 * it4;           // 0..31 j-pairs
        const int j0 = 2 * jp, j1 = 2 * jp + 1;
        tv0[it4] = (j0 < kN) ? hb2[j0 * 64 + lane] : make_float2(0.f, 0.f);
        tv1[it4] = (j1 < kN) ? hb2[j1 * 64 + lane] : make_float2(0.f, 0.f);
    }

    // ---------------- phase 1a: stage H hi/lo rows ----------------
    const float4* hg = reinterpret_cast<const float4*>(hb);
    #pragma unroll
    for (int it4 = 0; it4 < 4; ++it4) {
        const int idx = tid + it4 * 512;        // 0..2047 over 64 rows x 32 float4
        const int j   = idx >> 5;
        const int d4  = idx & 31;
        float4 v = make_float4(0.f, 0.f, 0.f, 0.f);
        if (j < kN) v = hg[j * 32 + d4];

        const uint32_t h0 = __float_as_uint(v.x) & 0xffff0000u;
        const uint32_t h1 = __float_as_uint(v.y) & 0xffff0000u;
        const uint32_t h2 = __float_as_uint(v.z) & 0xffff0000u;
        const uint32_t h3 = __float_as_uint(v.w) & 0xffff0000u;
        uint2 hiw;
        hiw.x = h1 | (h0 >> 16);
        hiw.y = h3 | (h2 >> 16);
        const float r0 = v.x - __uint_as_float(h0);
        const float r1 = v.y - __uint_as_float(h1);
        const float r2 = v.z - __uint_as_float(h2);
        const float r3 = v.w - __uint_as_float(h3);
        uint2 low;
        low.x = (__float_as_uint(r1) & 0xffff0000u) | (__float_as_uint(r0) >> 16);
        low.y = (__float_as_uint(r3) & 0xffff0000u) | (__float_as_uint(r2) >> 16);
        *reinterpret_cast<uint2*>(&Hhi[j * HS16 + 4 * d4]) = hiw;
        *reinterpret_cast<uint2*>(&Hlo[j * HS16 + 4 * d4]) = low;
    }
    // ---------------- phase 1b: adj bytes ----------------
    for (int idx = tid; idx < 625; idx += 512) {          // 2500 ints as int4
        const int4 v = reinterpret_cast<const int4*>(adjb)[idx];
        const int e = 4 * idx;
        const int vv[4] = {v.x, v.y, v.z, v.w};
        #pragma unroll
        for (int p = 0; p < 4; ++p) {
            const int ee  = e + p;
            const int row = ee / kN;
            const int col = ee - kN * row;
            Ad[row * ADS + col] = (unsigned char)vv[p];
        }
    }
    __syncthreads();   // barrier #1

    // ---------------- phase 2: scores via MFMA; wave = (i-tile, K-half) ----------------
    // adj bytes -> packed registers (overlaps score loop)
    uint32_t adv[4];
    #pragma unroll
    for (int jt = 0; jt < 4; ++jt) {
        const int j = 16 * jt + f;
        uint32_t w = 0;
        #pragma unroll
        for (int reg = 0; reg < 4; ++reg) {
            const int ii  = i0 + 4 * g + reg;
            const int iic = (ii < kN) ? ii : (kN - 1);
            const uint32_t kv = (j < kN) ? (uint32_t)Ad[iic * ADS + j] : 0u;
            w |= kv << (8 * reg);
        }
        adv[jt] = w;
    }

    f32x4 acc[4][4];                            // [jt][rel]
    #pragma unroll
    for (int jt = 0; jt < 4; ++jt)
        #pragma unroll
        for (int k = 0; k < 4; ++k) acc[jt][k] = (f32x4){0.f, 0.f, 0.f, 0.f};

    #pragma unroll
    for (int ksl2 = 0; ksl2 < 2; ++ksl2) {
        const int dofs = 64 * kh + 32 * ksl2 + 8 * g;

        const float ha[8] = {hA[ksl2][0].x, hA[ksl2][0].y, hA[ksl2][0].z, hA[ksl2][0].w,
                             hA[ksl2][1].x, hA[ksl2][1].y, hA[ksl2][1].z, hA[ksl2][1].w};

        short8 qh[4], ql[4];
        #pragma unroll
        for (int k = 0; k < 4; ++k) {
            const float aa[8] = {qa[ksl2][k][0].x, qa[ksl2][k][0].y, qa[ksl2][k][0].z, qa[ksl2][k][0].w,
                                 qa[ksl2][k][1].x, qa[ksl2][k][1].y, qa[ksl2][k][1].z, qa[ksl2][k][1].w};
            Pack8 ph, pl;
            #pragma unroll
            for (int p = 0; p < 4; ++p) {
                const float q0 = ha[2 * p]     * aa[2 * p];
                const float q1 = ha[2 * p + 1] * aa[2 * p + 1];
                const uint32_t b0 = __float_as_uint(q0) & 0xffff0000u;
                const uint32_t b1 = __float_as_uint(q1) & 0xffff0000u;
                ph.u[p] = b1 | (b0 >> 16);
                const float s0 = q0 - __uint_as_float(b0);
                const float s1 = q1 - __uint_as_float(b1);
                pl.u[p] = (__float_as_uint(s1) & 0xffff0000u) | (__float_as_uint(s0) >> 16);
            }
            qh[k] = ph.s;
            ql[k] = pl.s;
        }

        #pragma unroll
        for (int jt = 0; jt < 4; ++jt) {
            const int jrow = 16 * jt + f;       // rows>=50 zeroed in LDS
            const short8 bh = *reinterpret_cast<const short8*>(&Hhi[jrow * HS16 + dofs]);
            const short8 bl = *reinterpret_cast<const short8*>(&Hlo[jrow * HS16 + dofs]);
            #pragma unroll
            for (int k = 0; k < 4; ++k) {
                acc[jt][k] = __builtin_amdgcn_mfma_f32_16x16x32_bf16(qh[k], bh, acc[jt][k], 0, 0, 0);
                acc[jt][k] = __builtin_amdgcn_mfma_f32_16x16x32_bf16(qh[k], bl, acc[jt][k], 0, 0, 0);
                acc[jt][k] = __builtin_amdgcn_mfma_f32_16x16x32_bf16(ql[k], bh, acc[jt][k], 0, 0, 0);
            }
        }
    }

    // select on K-partial (commutes with K-sum) using packed register adj
    f32x4 spart[4];
    uint32_t vmask = 0;
    #pragma unroll
    for (int jt = 0; jt < 4; ++jt) {
        #pragma unroll
        for (int reg = 0; reg < 4; ++reg) {
            const int kv = (int)((adv[jt] >> (8 * reg)) & 0xffu);
            const bool valid = (kv >= 1) && (kv <= 4);
            spart[jt][reg] = (kv == 1) ? acc[jt][0][reg]
                           : (kv == 2) ? acc[jt][1][reg]
                           : (kv == 3) ? acc[jt][2][reg]
                           : (kv == 4) ? acc[jt][3][reg] : 0.f;
            vmask |= (valid ? 1u : 0u) << (4 * jt + reg);
        }
    }

    // ---------------- Hti write-late (T14): pack + LDS-write under barrier #2 ----------------
    #pragma unroll
    for (int it4 = 0; it4 < 4; ++it4) {
        const int jp = wid + 8 * it4;
        const int j0 = 2 * jp;
        const int d2 = lane;
        uint2 wa, wb;
        wa.x = pack_hl(tv0[it4].x); wa.y = pack_hl(tv1[it4].x);   // row d=2d2, cols j0,j0+1
        wb.x = pack_hl(tv0[it4].y); wb.y = pack_hl(tv1[it4].y);   // row d=2d2+1
        *reinterpret_cast<uint2*>(&Hti[(2 * d2 + 0) * HTW + j0]) = wa;
        *reinterpret_cast<uint2*>(&Hti[(2 * d2 + 1) * HTW + j0]) = wb;
    }

    // pairwise K-half exchange
    #pragma unroll
    for (int jt = 0; jt < 4; ++jt)
        *reinterpret_cast<f32x4*>(&Xch[wid][lane][4 * jt]) = spart[jt];
    __syncthreads();   // barrier #2 (orders Xch AND Hti)

    // ---------------- phase 3: sum halves + leaky + mask + in-register softmax ----------------
    float s[4][4];
    #pragma unroll
    for (int jt = 0; jt < 4; ++jt) {
        const f32x4 o = *reinterpret_cast<const f32x4*>(&Xch[wid ^ 4][lane][4 * jt]);
        #pragma unroll
        for (int reg = 0; reg < 4; ++reg) {
            const float x  = spart[jt][reg] + o[reg];
            const float lx = (x > 0.f) ? x : kSlope * x;
            s[jt][reg] = ((vmask >> (4 * jt + reg)) & 1u) ? lx : kNeg;
        }
    }

    #pragma unroll
    for (int reg = 0; reg < 4; ++reg) {
        float m = fmaxf(fmaxf(s[0][reg], s[1][reg]), fmaxf(s[2][reg], s[3][reg]));
        #pragma unroll
        for (int o = 1; o < 16; o <<= 1) m = fmaxf(m, __shfl_xor(m, o));

        float e[4];
        float t = 0.f;
        #pragma unroll
        for (int jt = 0; jt < 4; ++jt) {
            const int j = 16 * jt + f;
            e[jt] = (j < kN) ? __expf(s[jt][reg] - m) : 0.f;  // all-masked -> uniform (matches ref)
            t += e[jt];
        }
        #pragma unroll
        for (int o = 1; o < 16; o <<= 1) t += __shfl_xor(t, o);

        const float inv = 1.0f / t;
        #pragma unroll
        for (int jt = 0; jt < 4; ++jt) {
            uint32_t u = __float_as_uint(e[jt] * inv);
            u += 0x7fffu + ((u >> 16) & 1u);    // bf16 round-to-nearest
            Pw2[wid][(4 * g + reg) * PW + 16 * jt + f] = (unsigned short)(u >> 16);
        }
    }

    // ---------------- phase 4: PV via MFMA; wave handles d-half = kh ----------------
    {
        const int db = 64 * kh;

        const short8 af0 = *reinterpret_cast<const short8*>(&Pw2[wid][f * PW + 0  + 8 * g]);
        const short8 af1 = *reinterpret_cast<const short8*>(&Pw2[wid][f * PW + 32 + 8 * g]);

        f32x4 acc2[4];
        #pragma unroll
        for (int dt = 0; dt < 4; ++dt) acc2[dt] = (f32x4){0.f, 0.f, 0.f, 0.f};

        #pragma unroll
        for (int dt = 0; dt < 4; ++dt) {
            const int drow = db + 16 * dt + f;
            #pragma unroll
            for (int jc = 0; jc < 2; ++jc) {
                const uint32_t* hp = &Hti[drow * HTW + 32 * jc + 8 * g];
                const uint2 u01 = *reinterpret_cast<const uint2*>(hp + 0);
                const uint2 u23 = *reinterpret_cast<const uint2*>(hp + 2);
                const uint2 u45 = *reinterpret_cast<const uint2*>(hp + 4);
                const uint2 u67 = *reinterpret_cast<const uint2*>(hp + 6);
                Pack8 bh, bl;
                bh.u[0] = (u01.x & 0xffffu) | (u01.y << 16);
                bl.u[0] = (u01.x >> 16)     | (u01.y & 0xffff0000u);
                bh.u[1] = (u23.x & 0xffffu) | (u23.y << 16);
                bl.u[1] = (u23.x >> 16)     | (u23.y & 0xffff0000u);
                bh.u[2] = (u45.x & 0xffffu) | (u45.y << 16);
                bl.u[2] = (u45.x >> 16)     | (u45.y & 0xffff0000u);
                bh.u[3] = (u67.x & 0xffffu) | (u67.y << 16);
                bl.u[3] = (u67.x >> 16)     | (u67.y & 0xffff0000u);
                const short8 a8 = jc ? af1 : af0;
                acc2[dt] = __builtin_amdgcn_mfma_f32_16x16x32_bf16(a8, bh.s, acc2[dt], 0, 0, 0);
                acc2[dt] = __builtin_amdgcn_mfma_f32_16x16x32_bf16(a8, bl.s, acc2[dt], 0, 0, 0);
            }
        }

        // stores: D[row=4g+reg -> i][col=f -> d]
        #pragma unroll
        for (int reg = 0; reg < 4; ++reg) {
            const int ii = 16 * it + 4 * g + reg;
            if (ii < kN) {
                #pragma unroll
                for (int dt = 0; dt < 4; ++dt)
                    outb[ii * kD + db + 16 * dt + f] = acc2[dt][reg];
            }
        }
    }
}

extern "C" void kernel_launch(void* const* d_in, const int* in_sizes, int n_in,
                              void* d_out, int out_size, void* d_ws, size_t ws_size,
                              hipStream_t stream) {
    const float* hidden = reinterpret_cast<const float*>(d_in[0]);
    const int*   adjp   = reinterpret_cast<const int*>(d_in[1]);
    const float* a0     = reinterpret_cast<const float*>(d_in[2]);
    const float* a1     = reinterpret_cast<const float*>(d_in[3]);
    const float* a2     = reinterpret_cast<const float*>(d_in[4]);
    const float* a3     = reinterpret_cast<const float*>(d_in[5]);
    float*       outp   = reinterpret_cast<float*>(d_out);

    gat_v16_kernel<<<dim3(256), dim3(512), 0, stream>>>(
        hidden, adjp, a0, a1, a2, a3, outp);
}

// Round 17
// 16.093 us; speedup vs baseline: 1.0564x; 1.0564x over previous
//
#include <hip/hip_runtime.h>
#include <stdint.h>

typedef __attribute__((ext_vector_type(8))) short short8;
typedef __attribute__((ext_vector_type(4))) float f32x4;

namespace {
constexpr int   kN     = 50;
constexpr int   kD     = 128;
constexpr float kNeg   = -9.0e15f;
constexpr float kSlope = 0.2f;
constexpr int   HS16   = 136;   // Hhi/Hlo row stride (shorts), 16B-aligned rows
constexpr int   ADS    = 52;    // adj byte stride
constexpr int   HTW    = 66;    // Hti row stride (u32 words)
constexpr int   PW     = 72;    // Pw2 row stride (shorts)
}

union Pack8 { uint32_t u[4]; short8 s; };

// interleaved hi|lo bf16 pack: low short = hi-bf16(v), high short = lo-bf16(v - hi)
__device__ __forceinline__ uint32_t pack_hl(float v) {
    const uint32_t b  = __float_as_uint(v);
    const uint32_t hi = b & 0xffff0000u;
    const float    r  = v - __uint_as_float(hi);
    return (b >> 16) | (__float_as_uint(r) & 0xffff0000u);
}

__global__ __launch_bounds__(512)
void gat_v17_kernel(const float* __restrict__ hidden,
                    const int*   __restrict__ adj,
                    const float* __restrict__ a0,
                    const float* __restrict__ a1,
                    const float* __restrict__ a2,
                    const float* __restrict__ a3,
                    float* __restrict__ out)
{
    __shared__ unsigned short Hhi[64 * HS16];   // 17.0 KB bf16 hi(H) rows, j>=50 zero
    __shared__ unsigned short Hlo[64 * HS16];   // 17.0 KB bf16 lo(H)
    __shared__ uint32_t       Hti[128 * HTW];   // 33.0 KB transposed H [d][j], hi|lo interleaved
    __shared__ unsigned char  Ad [kN * ADS];    //  2.5 KB adj bytes
    __shared__ float          Xch[8][64][16];   // 32.0 KB K-half partial exchange
    __shared__ unsigned short Pw2[8][16 * PW];  // 18.0 KB per-wave P [i][j] bf16
    // total ~120 KB -> 1 block/CU, 8 waves

    const int b    = blockIdx.x;
    const int tid  = threadIdx.x;
    const int lane = tid & 63;
    const int wid  = __builtin_amdgcn_readfirstlane(tid >> 6);  // 0..7
    const int g    = lane >> 4;
    const int f    = lane & 15;

    const float* __restrict__ hb   = hidden + (size_t)b * (kN * kD);
    const int*   __restrict__ adjb = adj    + (size_t)b * (kN * kN);
    float*       __restrict__ outb = out    + (size_t)b * (kN * kD);

    // ---------------- phase 1a: stage H hi/lo rows ----------------
    const float4* hg = reinterpret_cast<const float4*>(hb);
    #pragma unroll
    for (int it4 = 0; it4 < 4; ++it4) {
        const int idx = tid + it4 * 512;        // 0..2047 over 64 rows x 32 float4
        const int j   = idx >> 5;
        const int d4  = idx & 31;
        float4 v = make_float4(0.f, 0.f, 0.f, 0.f);
        if (j < kN) v = hg[j * 32 + d4];

        const uint32_t h0 = __float_as_uint(v.x) & 0xffff0000u;
        const uint32_t h1 = __float_as_uint(v.y) & 0xffff0000u;
        const uint32_t h2 = __float_as_uint(v.z) & 0xffff0000u;
        const uint32_t h3 = __float_as_uint(v.w) & 0xffff0000u;
        uint2 hiw;
        hiw.x = h1 | (h0 >> 16);
        hiw.y = h3 | (h2 >> 16);
        const float r0 = v.x - __uint_as_float(h0);
        const float r1 = v.y - __uint_as_float(h1);
        const float r2 = v.z - __uint_as_float(h2);
        const float r3 = v.w - __uint_as_float(h3);
        uint2 low;
        low.x = (__float_as_uint(r1) & 0xffff0000u) | (__float_as_uint(r0) >> 16);
        low.y = (__float_as_uint(r3) & 0xffff0000u) | (__float_as_uint(r2) >> 16);
        *reinterpret_cast<uint2*>(&Hhi[j * HS16 + 4 * d4]) = hiw;
        *reinterpret_cast<uint2*>(&Hlo[j * HS16 + 4 * d4]) = low;
    }
    // ---------------- phase 1b: adj bytes ----------------
    for (int idx = tid; idx < 625; idx += 512) {          // 2500 ints as int4
        const int4 v = reinterpret_cast<const int4*>(adjb)[idx];
        const int e = 4 * idx;
        const int vv[4] = {v.x, v.y, v.z, v.w};
        #pragma unroll
        for (int p = 0; p < 4; ++p) {
            const int ee  = e + p;
            const int row = ee / kN;
            const int col = ee - kN * row;
            Ad[row * ADS + col] = (unsigned char)vv[p];
        }
    }
    // ---------------- phase 1c (T14 issue-early): H transpose source -> registers ----------------
    const float2* hb2 = reinterpret_cast<const float2*>(hb);
    float2 tv0[4], tv1[4];
    #pragma unroll
    for (int it4 = 0; it4 < 4; ++it4) {
        const int jp = wid + 8 * it4;           // 0..31 j-pairs
        const int j0 = 2 * jp, j1 = 2 * jp + 1;
        tv0[it4] = (j0 < kN) ? hb2[j0 * 64 + lane] : make_float2(0.f, 0.f);
        tv1[it4] = (j1 < kN) ? hb2[j1 * 64 + lane] : make_float2(0.f, 0.f);
    }
    __syncthreads();   // barrier #1

    // ---------------- phase 2: scores via MFMA; wave = (i-tile, K-half) ----------------
    const int it   = wid & 3;
    const int kh   = wid >> 2;
    const int i0   = 16 * it;
    const int irow = (i0 + f < kN) ? (i0 + f) : (kN - 1);

    // adj bytes for this wave's 16x16x4 footprint -> registers (overlaps score loop)
    int adv[4][4];
    #pragma unroll
    for (int jt = 0; jt < 4; ++jt) {
        const int j = 16 * jt + f;
        #pragma unroll
        for (int reg = 0; reg < 4; ++reg) {
            const int ii  = i0 + 4 * g + reg;
            const int iic = (ii < kN) ? ii : (kN - 1);
            adv[jt][reg] = (j < kN) ? (int)Ad[iic * ADS + j] : 0;
        }
    }

    f32x4 acc[4][4];                            // [jt][rel]
    #pragma unroll
    for (int jt = 0; jt < 4; ++jt)
        #pragma unroll
        for (int k = 0; k < 4; ++k) acc[jt][k] = (f32x4){0.f, 0.f, 0.f, 0.f};

    const float* __restrict__ aks[4] = {a0, a1, a2, a3};

    #pragma unroll
    for (int ksl2 = 0; ksl2 < 2; ++ksl2) {
        const int dofs = 64 * kh + 32 * ksl2 + 8 * g;

        // A-side h_i reconstructed from Hhi+Hlo
        const short8 ah8 = *reinterpret_cast<const short8*>(&Hhi[irow * HS16 + dofs]);
        const short8 al8 = *reinterpret_cast<const short8*>(&Hlo[irow * HS16 + dofs]);
        float ha[8];
        #pragma unroll
        for (int p = 0; p < 8; ++p) {
            const uint32_t uh = ((uint32_t)(unsigned short)ah8[p]) << 16;
            const uint32_t ul = ((uint32_t)(unsigned short)al8[p]) << 16;
            ha[p] = __uint_as_float(uh) + __uint_as_float(ul);
        }

        short8 qh[4], ql[4];
        #pragma unroll
        for (int k = 0; k < 4; ++k) {
            const float4 av0 = *reinterpret_cast<const float4*>(aks[k] + dofs);
            const float4 av1 = *reinterpret_cast<const float4*>(aks[k] + dofs + 4);
            const float aa[8] = {av0.x, av0.y, av0.z, av0.w, av1.x, av1.y, av1.z, av1.w};
            Pack8 ph, pl;
            #pragma unroll
            for (int p = 0; p < 4; ++p) {
                const float q0 = ha[2 * p]     * aa[2 * p];
                const float q1 = ha[2 * p + 1] * aa[2 * p + 1];
                const uint32_t b0 = __float_as_uint(q0) & 0xffff0000u;
                const uint32_t b1 = __float_as_uint(q1) & 0xffff0000u;
                ph.u[p] = b1 | (b0 >> 16);
                const float s0 = q0 - __uint_as_float(b0);
                const float s1 = q1 - __uint_as_float(b1);
                pl.u[p] = (__float_as_uint(s1) & 0xffff0000u) | (__float_as_uint(s0) >> 16);
            }
            qh[k] = ph.s;
            ql[k] = pl.s;
        }

        #pragma unroll
        for (int jt = 0; jt < 4; ++jt) {
            const int jrow = 16 * jt + f;       // rows>=50 zeroed in LDS
            const short8 bh = *reinterpret_cast<const short8*>(&Hhi[jrow * HS16 + dofs]);
            const short8 bl = *reinterpret_cast<const short8*>(&Hlo[jrow * HS16 + dofs]);
            #pragma unroll
            for (int k = 0; k < 4; ++k) {
                acc[jt][k] = __builtin_amdgcn_mfma_f32_16x16x32_bf16(qh[k], bh, acc[jt][k], 0, 0, 0);
                acc[jt][k] = __builtin_amdgcn_mfma_f32_16x16x32_bf16(qh[k], bl, acc[jt][k], 0, 0, 0);
                acc[jt][k] = __builtin_amdgcn_mfma_f32_16x16x32_bf16(ql[k], bh, acc[jt][k], 0, 0, 0);
            }
        }
    }

    // select on K-partial (linear -> commutes with K-sum) using register adj
    f32x4 spart[4];
    uint32_t vmask = 0;
    #pragma unroll
    for (int jt = 0; jt < 4; ++jt) {
        #pragma unroll
        for (int reg = 0; reg < 4; ++reg) {
            const int kv = adv[jt][reg];
            const bool valid = (kv >= 1) && (kv <= 4);
            spart[jt][reg] = (kv == 1) ? acc[jt][0][reg]
                           : (kv == 2) ? acc[jt][1][reg]
                           : (kv == 3) ? acc[jt][2][reg]
                           : (kv == 4) ? acc[jt][3][reg] : 0.f;
            vmask |= (valid ? 1u : 0u) << (4 * jt + reg);
        }
    }

    // ---------------- phase 1c (T14 write-late): pack + LDS-write Hti under barrier #2 ----------------
    #pragma unroll
    for (int it4 = 0; it4 < 4; ++it4) {
        const int jp = wid + 8 * it4;
        const int j0 = 2 * jp;
        const int d2 = lane;
        uint2 wa, wb;
        wa.x = pack_hl(tv0[it4].x); wa.y = pack_hl(tv1[it4].x);   // row d=2d2, cols j0,j0+1
        wb.x = pack_hl(tv0[it4].y); wb.y = pack_hl(tv1[it4].y);   // row d=2d2+1
        *reinterpret_cast<uint2*>(&Hti[(2 * d2 + 0) * HTW + j0]) = wa;
        *reinterpret_cast<uint2*>(&Hti[(2 * d2 + 1) * HTW + j0]) = wb;
    }

    // pairwise K-half exchange
    #pragma unroll
    for (int jt = 0; jt < 4; ++jt)
        *reinterpret_cast<f32x4*>(&Xch[wid][lane][4 * jt]) = spart[jt];
    __syncthreads();   // barrier #2 (orders Xch AND Hti)

    // ---------------- phase 3: sum halves + leaky + mask + in-register softmax ----------------
    float s[4][4];
    #pragma unroll
    for (int jt = 0; jt < 4; ++jt) {
        const f32x4 o = *reinterpret_cast<const f32x4*>(&Xch[wid ^ 4][lane][4 * jt]);
        #pragma unroll
        for (int reg = 0; reg < 4; ++reg) {
            const float x  = spart[jt][reg] + o[reg];
            const float lx = (x > 0.f) ? x : kSlope * x;
            s[jt][reg] = ((vmask >> (4 * jt + reg)) & 1u) ? lx : kNeg;
        }
    }

    #pragma unroll
    for (int reg = 0; reg < 4; ++reg) {
        float m = fmaxf(fmaxf(s[0][reg], s[1][reg]), fmaxf(s[2][reg], s[3][reg]));
        #pragma unroll
        for (int o = 1; o < 16; o <<= 1) m = fmaxf(m, __shfl_xor(m, o));

        float e[4];
        float t = 0.f;
        #pragma unroll
        for (int jt = 0; jt < 4; ++jt) {
            const int j = 16 * jt + f;
            e[jt] = (j < kN) ? __expf(s[jt][reg] - m) : 0.f;  // all-masked -> uniform (matches ref)
            t += e[jt];
        }
        #pragma unroll
        for (int o = 1; o < 16; o <<= 1) t += __shfl_xor(t, o);

        const float inv = 1.0f / t;
        #pragma unroll
        for (int jt = 0; jt < 4; ++jt) {
            uint32_t u = __float_as_uint(e[jt] * inv);
            u += 0x7fffu + ((u >> 16) & 1u);    // bf16 round-to-nearest
            // P in [i][j] layout -> A-frag-ready rows (same-wave RAW, lgkmcnt-ordered)
            Pw2[wid][(4 * g + reg) * PW + 16 * jt + f] = (unsigned short)(u >> 16);
        }
    }

    // ---------------- phase 4: PV via MFMA; wave handles d-half = kh ----------------
    {
        const int db = 64 * kh;

        // A-frags: P[i=f][j=8g+p (+32jc)] -- one b128 each
        const short8 af0 = *reinterpret_cast<const short8*>(&Pw2[wid][f * PW + 0  + 8 * g]);
        const short8 af1 = *reinterpret_cast<const short8*>(&Pw2[wid][f * PW + 32 + 8 * g]);

        f32x4 acc2[4];
        #pragma unroll
        for (int dt = 0; dt < 4; ++dt) acc2[dt] = (f32x4){0.f, 0.f, 0.f, 0.f};

        #pragma unroll
        for (int dt = 0; dt < 4; ++dt) {
            const int drow = db + 16 * dt + f;
            #pragma unroll
            for (int jc = 0; jc < 2; ++jc) {
                const uint32_t* hp = &Hti[drow * HTW + 32 * jc + 8 * g];
                const uint2 u01 = *reinterpret_cast<const uint2*>(hp + 0);
                const uint2 u23 = *reinterpret_cast<const uint2*>(hp + 2);
                const uint2 u45 = *reinterpret_cast<const uint2*>(hp + 4);
                const uint2 u67 = *reinterpret_cast<const uint2*>(hp + 6);
                Pack8 bh, bl;
                bh.u[0] = (u01.x & 0xffffu) | (u01.y << 16);
                bl.u[0] = (u01.x >> 16)     | (u01.y & 0xffff0000u);
                bh.u[1] = (u23.x & 0xffffu) | (u23.y << 16);
                bl.u[1] = (u23.x >> 16)     | (u23.y & 0xffff0000u);
                bh.u[2] = (u45.x & 0xffffu) | (u45.y << 16);
                bl.u[2] = (u45.x >> 16)     | (u45.y & 0xffff0000u);
                bh.u[3] = (u67.x & 0xffffu) | (u67.y << 16);
                bl.u[3] = (u67.x >> 16)     | (u67.y & 0xffff0000u);
                const short8 a8 = jc ? af1 : af0;
                acc2[dt] = __builtin_amdgcn_mfma_f32_16x16x32_bf16(a8, bh.s, acc2[dt], 0, 0, 0);
                acc2[dt] = __builtin_amdgcn_mfma_f32_16x16x32_bf16(a8, bl.s, acc2[dt], 0, 0, 0);
            }
        }

        // stores: D[row=4g+reg -> i][col=f -> d]; coalesced 64B segments per (dt,reg)
        #pragma unroll
        for (int reg = 0; reg < 4; ++reg) {
            const int ii = 16 * it + 4 * g + reg;
            if (ii < kN) {
                #pragma unroll
                for (int dt = 0; dt < 4; ++dt)
                    outb[ii * kD + db + 16 * dt + f] = acc2[dt][reg];
            }
        }
    }
}

extern "C" void kernel_launch(void* const* d_in, const int* in_sizes, int n_in,
                              void* d_out, int out_size, void* d_ws, size_t ws_size,
                              hipStream_t stream) {
    const float* hidden = reinterpret_cast<const float*>(d_in[0]);
    const int*   adjp   = reinterpret_cast<const int*>(d_in[1]);
    const float* a0     = reinterpret_cast<const float*>(d_in[2]);
    const float* a1     = reinterpret_cast<const float*>(d_in[3]);
    const float* a2     = reinterpret_cast<const float*>(d_in[4]);
    const float* a3     = reinterpret_cast<const float*>(d_in[5]);
    float*       outp   = reinterpret_cast<float*>(d_out);

    gat_v17_kernel<<<dim3(256), dim3(512), 0, stream>>>(
        hidden, adjp, a0, a1, a2, a3, outp);
}